// Round 4
// baseline (98.733 us; speedup 1.0000x reference)
//
#include <hip/hip_runtime.h>
#include <math.h>

// Problem constants
#define H 32
#define W 32
#define OH 94
#define OW 94
#define NMESH (OH * OW)   // 8836
#define B 4
#define M 4096
#define BM (B * M)        // 16384

// Mesh chunking: 128 chunks of ceil(8836/128)=70, padded to 72 (div by 4).
// Small chunks keep the per-CU scalar-L1 footprint at 4 blocks * 1.15 KB =
// 4.6 KB << 16 KB sL1 (R3's 37 KB footprint thrashed sL1 at ~43 cyc/miss).
#define NCHUNK 128
#define CH 70
#define CHPAD 72
#define BPB (NCHUNK * CHPAD)   // per-batch padded mesh entries = 9216
#define MESH_TOTAL (B * BPB)   // 36864

// pc points per thread in dist_kernel: 32 VALU ops per 16 scalar bytes.
#define P 8

// Kernel 1: bilinear mesh refine -> float4(-2x, -2y, -2z, ||m||^2); zero out.
// Premultiply by -2 (exact in fp32): partial = fma(px,-2mx, fma(py,-2my, fma(pz,-2mz, ||m||^2))).
__global__ __launch_bounds__(256) void mesh_init_kernel(
        const float* __restrict__ nm, float4* __restrict__ mesh4,
        float* __restrict__ out) {
    int e = blockIdx.x * 256 + threadIdx.x;
    if (e == 0) out[0] = 0.0f;
    if (e >= MESH_TOTAL) return;

    int b = e / BPB;
    int r = e - b * BPB;
    int chunk = r / CHPAD;
    int k = r - chunk * CHPAD;
    int n = chunk * CH + k;
    if (k >= CH || n >= NMESH) {  // padding sentinel: never the min
        mesh4[e] = make_float4(0.f, 0.f, 0.f, 3.0e38f);
        return;
    }
    int oy = n / OW;
    int ox = n - oy * OW;
    float ys = (float)oy / 3.0f;
    float xs = (float)ox / 3.0f;
    int y0 = (int)floorf(ys); if (y0 > H - 2) y0 = H - 2;
    int x0 = (int)floorf(xs); if (x0 > W - 2) x0 = W - 2;
    float wy = ys - (float)y0;
    float wx = xs - (float)x0;

    const float* base = nm + b * 3 * H * W;
    float vals[3];
#pragma unroll
    for (int c = 0; c < 3; ++c) {
        const float* p = base + c * H * W + y0 * W + x0;
        float v00 = p[0], v01 = p[1], v10 = p[W], v11 = p[W + 1];
        float top = v00 * (1.0f - wx) + v01 * wx;
        float bot = v10 * (1.0f - wx) + v11 * wx;
        vals[c] = top * (1.0f - wy) + bot * wy;
    }
    float nrm = vals[0] * vals[0] + vals[1] * vals[1] + vals[2] * vals[2];
    mesh4[e] = make_float4(-2.0f * vals[0], -2.0f * vals[1], -2.0f * vals[2], nrm);
}

// Kernel 2: P=8 pc points per thread, min over one 72-point mesh chunk of
// (||m||^2 - 2 p.m). Mesh reads are wave-uniform -> scalar s_load path; each
// 16-byte mesh entry feeds 32 VALU ops, so sL1-hit latency is fully hidden.
__global__ __launch_bounds__(256) void dist_kernel(
        const float* __restrict__ pc, const float4* __restrict__ mesh4,
        float* __restrict__ minpart) {
    int b = blockIdx.z;                            // 4
    int chunk = blockIdx.x;                        // 128
    int i0 = blockIdx.y * (256 * P) + threadIdx.x; // pc base point
    const float4* mp = mesh4 + b * BPB + chunk * CHPAD;

    float px[P], py[P], pz[P], m[P];
#pragma unroll
    for (int p = 0; p < P; ++p) {
        int i = i0 + p * 256;
        px[p] = pc[(b * 3 + 0) * M + i];
        py[p] = pc[(b * 3 + 1) * M + i];
        pz[p] = pc[(b * 3 + 2) * M + i];
        m[p] = 3.0e38f;
    }

    for (int j = 0; j < CHPAD; j += 4) {
        float4 a0 = mp[j + 0];
        float4 a1 = mp[j + 1];
        float4 a2 = mp[j + 2];
        float4 a3 = mp[j + 3];
#pragma unroll
        for (int p = 0; p < P; ++p) {
            float s0 = fmaf(px[p], a0.x, fmaf(py[p], a0.y, fmaf(pz[p], a0.z, a0.w)));
            float s1 = fmaf(px[p], a1.x, fmaf(py[p], a1.y, fmaf(pz[p], a1.z, a1.w)));
            float s2 = fmaf(px[p], a2.x, fmaf(py[p], a2.y, fmaf(pz[p], a2.z, a2.w)));
            float s3 = fmaf(px[p], a3.x, fmaf(py[p], a3.y, fmaf(pz[p], a3.z, a3.w)));
            m[p] = fminf(fminf(fminf(m[p], s0), fminf(s1, s2)), s3);
        }
    }

#pragma unroll
    for (int p = 0; p < P; ++p)
        minpart[(chunk * B + b) * M + i0 + p * 256] = m[p];
}

// Kernel 3: fold 128 chunk-partials, add ||p||^2, mean via block reduce + atomicAdd.
__global__ __launch_bounds__(256) void reduce_kernel(
        const float* __restrict__ pc, const float* __restrict__ minpart,
        float* __restrict__ out) {
    int e = blockIdx.x * 256 + threadIdx.x;  // [0, 16384)
    int b = e >> 12;
    int i = e & (M - 1);

    float v = 3.0e38f;
#pragma unroll 8
    for (int c = 0; c < NCHUNK; ++c)
        v = fminf(v, minpart[(c * B + b) * M + i]);

    float px = pc[(b * 3 + 0) * M + i];
    float py = pc[(b * 3 + 1) * M + i];
    float pz = pc[(b * 3 + 2) * M + i];
    float pn = fmaf(px, px, fmaf(py, py, pz * pz));
    float d = v + pn;

    // wave64 reduce
    for (int off = 32; off > 0; off >>= 1)
        d += __shfl_down(d, off, 64);
    __shared__ float smem[4];
    int lane = threadIdx.x & 63;
    int wid = threadIdx.x >> 6;
    if (lane == 0) smem[wid] = d;
    __syncthreads();
    if (threadIdx.x == 0) {
        float s = (smem[0] + smem[1]) + (smem[2] + smem[3]);
        atomicAdd(out, s * (1.0f / (float)BM));
    }
}

extern "C" void kernel_launch(void* const* d_in, const int* in_sizes, int n_in,
                              void* d_out, int out_size, void* d_ws, size_t ws_size,
                              hipStream_t stream) {
    const float* nm = (const float*)d_in[0];   // (4,3,32,32)
    const float* pc = (const float*)d_in[1];   // (4,3,4096)
    float* out = (float*)d_out;                // scalar

    float* minpart = (float*)d_ws;                                        // 8 MiB
    float4* mesh4 = (float4*)((char*)d_ws + (size_t)NCHUNK * BM * sizeof(float));

    int g1 = (MESH_TOTAL + 255) / 256;
    mesh_init_kernel<<<g1, 256, 0, stream>>>(nm, mesh4, out);

    // grid: 128 chunks x 2 pc-tiles x 4 batches = 1024 blocks (4 blocks/CU)
    dist_kernel<<<dim3(NCHUNK, M / (256 * P), B), 256, 0, stream>>>(pc, mesh4, minpart);

    reduce_kernel<<<BM / 256, 256, 0, stream>>>(pc, minpart, out);
}

// Round 5
// 92.644 us; speedup vs baseline: 1.0657x; 1.0657x over previous
//
#include <hip/hip_runtime.h>
#include <math.h>

// Problem constants
#define H 32
#define W 32
#define OH 94
#define OW 94
#define NMESH (OH * OW)   // 8836
#define B 4
#define M 4096
#define BM (B * M)        // 16384

// Mesh chunking: 128 chunks of ceil(8836/128)=70, padded to 72 (div by 4).
#define NCHUNK 128
#define CH 70
#define CHPAD 72
#define BPB (NCHUNK * CHPAD)   // per-batch padded mesh entries = 9216
#define MESH_TOTAL (B * BPB)   // 36864

// pc points per thread in dist_kernel.
#define P 8

// Kernel 1: bilinear mesh refine -> float4(-2x, -2y, -2z, ||m||^2); zero out.
// Premultiply by -2 (exact in fp32): partial = fma(px,-2mx, fma(py,-2my, fma(pz,-2mz, ||m||^2))).
__global__ __launch_bounds__(256) void mesh_init_kernel(
        const float* __restrict__ nm, float4* __restrict__ mesh4,
        float* __restrict__ out) {
    int e = blockIdx.x * 256 + threadIdx.x;
    if (e == 0) out[0] = 0.0f;
    if (e >= MESH_TOTAL) return;

    int b = e / BPB;
    int r = e - b * BPB;
    int chunk = r / CHPAD;
    int k = r - chunk * CHPAD;
    int n = chunk * CH + k;
    if (k >= CH || n >= NMESH) {  // padding sentinel: never the min
        mesh4[e] = make_float4(0.f, 0.f, 0.f, 3.0e38f);
        return;
    }
    int oy = n / OW;
    int ox = n - oy * OW;
    float ys = (float)oy / 3.0f;
    float xs = (float)ox / 3.0f;
    int y0 = (int)floorf(ys); if (y0 > H - 2) y0 = H - 2;
    int x0 = (int)floorf(xs); if (x0 > W - 2) x0 = W - 2;
    float wy = ys - (float)y0;
    float wx = xs - (float)x0;

    const float* base = nm + b * 3 * H * W;
    float vals[3];
#pragma unroll
    for (int c = 0; c < 3; ++c) {
        const float* p = base + c * H * W + y0 * W + x0;
        float v00 = p[0], v01 = p[1], v10 = p[W], v11 = p[W + 1];
        float top = v00 * (1.0f - wx) + v01 * wx;
        float bot = v10 * (1.0f - wx) + v11 * wx;
        vals[c] = top * (1.0f - wy) + bot * wy;
    }
    float nrm = vals[0] * vals[0] + vals[1] * vals[1] + vals[2] * vals[2];
    mesh4[e] = make_float4(-2.0f * vals[0], -2.0f * vals[1], -2.0f * vals[2], nrm);
}

// Kernel 2: P=8 pc points per thread; mesh chunk staged in LDS.
// Rationale (R3/R4 post-mortem): wave-uniform global reads become SMEM s_loads,
// and SMEM completes OUT-OF-ORDER -> only lgkmcnt(0) full-drain waits -> no
// software pipelining possible (~42 us). DS ops complete IN-ORDER, so
// ds_read_b128 results can be consumed under partial lgkmcnt(N) waits; the
// compiler pipelines them. Wave-uniform LDS addresses broadcast (conflict-free).
__global__ __launch_bounds__(256) void dist_kernel(
        const float* __restrict__ pc, const float4* __restrict__ mesh4,
        float* __restrict__ minpart) {
    int b = blockIdx.z;                            // 4
    int chunk = blockIdx.x;                        // 128
    int i0 = blockIdx.y * (256 * P) + threadIdx.x; // pc base point

    __shared__ float4 sm[CHPAD];

    // Issue pc loads first (independent of the staging load).
    float px[P], py[P], pz[P], m[P];
#pragma unroll
    for (int p = 0; p < P; ++p) {
        int i = i0 + p * 256;
        px[p] = pc[(b * 3 + 0) * M + i];
        py[p] = pc[(b * 3 + 1) * M + i];
        pz[p] = pc[(b * 3 + 2) * M + i];
        m[p] = 3.0e38f;
    }

    // Stage the 72-entry chunk (1152 B) into LDS, one float4 per low thread.
    if (threadIdx.x < CHPAD)
        sm[threadIdx.x] = mesh4[b * BPB + chunk * CHPAD + threadIdx.x];
    __syncthreads();

    for (int j = 0; j < CHPAD; j += 4) {
        float4 a0 = sm[j + 0];
        float4 a1 = sm[j + 1];
        float4 a2 = sm[j + 2];
        float4 a3 = sm[j + 3];
#pragma unroll
        for (int p = 0; p < P; ++p) {
            float s0 = fmaf(px[p], a0.x, fmaf(py[p], a0.y, fmaf(pz[p], a0.z, a0.w)));
            float s1 = fmaf(px[p], a1.x, fmaf(py[p], a1.y, fmaf(pz[p], a1.z, a1.w)));
            float s2 = fmaf(px[p], a2.x, fmaf(py[p], a2.y, fmaf(pz[p], a2.z, a2.w)));
            float s3 = fmaf(px[p], a3.x, fmaf(py[p], a3.y, fmaf(pz[p], a3.z, a3.w)));
            m[p] = fminf(fminf(fminf(m[p], s0), fminf(s1, s2)), s3);
        }
    }

#pragma unroll
    for (int p = 0; p < P; ++p)
        minpart[(chunk * B + b) * M + i0 + p * 256] = m[p];
}

// Kernel 3: fold 128 chunk-partials, add ||p||^2, mean via block reduce + atomicAdd.
__global__ __launch_bounds__(256) void reduce_kernel(
        const float* __restrict__ pc, const float* __restrict__ minpart,
        float* __restrict__ out) {
    int e = blockIdx.x * 256 + threadIdx.x;  // [0, 16384)
    int b = e >> 12;
    int i = e & (M - 1);

    float v = 3.0e38f;
#pragma unroll 8
    for (int c = 0; c < NCHUNK; ++c)
        v = fminf(v, minpart[(c * B + b) * M + i]);

    float px = pc[(b * 3 + 0) * M + i];
    float py = pc[(b * 3 + 1) * M + i];
    float pz = pc[(b * 3 + 2) * M + i];
    float pn = fmaf(px, px, fmaf(py, py, pz * pz));
    float d = v + pn;

    // wave64 reduce
    for (int off = 32; off > 0; off >>= 1)
        d += __shfl_down(d, off, 64);
    __shared__ float smem[4];
    int lane = threadIdx.x & 63;
    int wid = threadIdx.x >> 6;
    if (lane == 0) smem[wid] = d;
    __syncthreads();
    if (threadIdx.x == 0) {
        float s = (smem[0] + smem[1]) + (smem[2] + smem[3]);
        atomicAdd(out, s * (1.0f / (float)BM));
    }
}

extern "C" void kernel_launch(void* const* d_in, const int* in_sizes, int n_in,
                              void* d_out, int out_size, void* d_ws, size_t ws_size,
                              hipStream_t stream) {
    const float* nm = (const float*)d_in[0];   // (4,3,32,32)
    const float* pc = (const float*)d_in[1];   // (4,3,4096)
    float* out = (float*)d_out;                // scalar

    float* minpart = (float*)d_ws;                                        // 8 MiB
    float4* mesh4 = (float4*)((char*)d_ws + (size_t)NCHUNK * BM * sizeof(float));

    int g1 = (MESH_TOTAL + 255) / 256;
    mesh_init_kernel<<<g1, 256, 0, stream>>>(nm, mesh4, out);

    // grid: 128 chunks x 2 pc-tiles x 4 batches = 1024 blocks (4 blocks/CU)
    dist_kernel<<<dim3(NCHUNK, M / (256 * P), B), 256, 0, stream>>>(pc, mesh4, minpart);

    reduce_kernel<<<BM / 256, 256, 0, stream>>>(pc, minpart, out);
}

// Round 6
// 91.452 us; speedup vs baseline: 1.0796x; 1.0130x over previous
//
#include <hip/hip_runtime.h>
#include <math.h>

// Problem constants
#define H 32
#define W 32
#define OH 94
#define OW 94
#define NMESH (OH * OW)   // 8836
#define B 4
#define M 4096
#define BM (B * M)        // 16384

// Mesh chunking: 128 chunks of 70 points, padded to 72 (div by 4).
#define NCHUNK 128
#define CH 70
#define CHPAD 72

// pc points per thread: P=4 keeps VGPRs <= 64 so we hit 8 waves/SIMD
// (R1-R5 evidence: occupancy is the dominant lever; 2->8 waves = 2.9x).
#define P 4

// Fused kernel: refine mesh chunk in-block -> LDS, then min over chunk of
// (||m||^2 - 2 p.m) for P pc points/thread. LDS (not SMEM/s_load) because DS
// completes in-order -> partial lgkmcnt waits -> compiler can pipeline;
// wave-uniform LDS reads broadcast conflict-free.
__global__ __launch_bounds__(256, 8) void dist_kernel(
        const float* __restrict__ nm, const float* __restrict__ pc,
        float* __restrict__ minpart, float* __restrict__ out) {
    int b = blockIdx.z;                            // 4
    int chunk = blockIdx.x;                        // 128
    int i0 = blockIdx.y * (256 * P) + threadIdx.x; // pc base point

    if (blockIdx.x == 0 && blockIdx.y == 0 && blockIdx.z == 0 && threadIdx.x == 0)
        out[0] = 0.0f;  // reduce_kernel (stream-ordered after us) accumulates here

    __shared__ float4 sm[CHPAD];

    // --- Stage: refine this block's 70 mesh points from raw network_mesh ---
    // Store (-2x, -2y, -2z, ||m||^2): premultiply by -2 (exact in fp32) makes
    // the distance partial a pure 3-fma chain.
    if (threadIdx.x < CHPAD) {
        int k = threadIdx.x;
        int n = chunk * CH + k;
        if (k >= CH || n >= NMESH) {
            sm[k] = make_float4(0.f, 0.f, 0.f, 3.0e38f);  // sentinel: never min
        } else {
            int oy = n / OW;
            int ox = n - oy * OW;
            float ys = (float)oy / 3.0f;
            float xs = (float)ox / 3.0f;
            int y0 = (int)floorf(ys); if (y0 > H - 2) y0 = H - 2;
            int x0 = (int)floorf(xs); if (x0 > W - 2) x0 = W - 2;
            float wy = ys - (float)y0;
            float wx = xs - (float)x0;
            const float* base = nm + b * 3 * H * W + y0 * W + x0;
            float vals[3];
#pragma unroll
            for (int c = 0; c < 3; ++c) {
                const float* p = base + c * H * W;
                float v00 = p[0], v01 = p[1], v10 = p[W], v11 = p[W + 1];
                float top = v00 * (1.0f - wx) + v01 * wx;
                float bot = v10 * (1.0f - wx) + v11 * wx;
                vals[c] = top * (1.0f - wy) + bot * wy;
            }
            float nrm = vals[0] * vals[0] + vals[1] * vals[1] + vals[2] * vals[2];
            sm[k] = make_float4(-2.f * vals[0], -2.f * vals[1], -2.f * vals[2], nrm);
        }
    }

    // pc loads (independent of staging; issue before the barrier)
    float px[P], py[P], pz[P], m[P];
#pragma unroll
    for (int p = 0; p < P; ++p) {
        int i = i0 + p * 256;
        px[p] = pc[(b * 3 + 0) * M + i];
        py[p] = pc[(b * 3 + 1) * M + i];
        pz[p] = pc[(b * 3 + 2) * M + i];
        m[p] = 3.0e38f;
    }
    __syncthreads();

    for (int j = 0; j < CHPAD; j += 4) {
        float4 a0 = sm[j + 0];
        float4 a1 = sm[j + 1];
        float4 a2 = sm[j + 2];
        float4 a3 = sm[j + 3];
#pragma unroll
        for (int p = 0; p < P; ++p) {
            float s0 = fmaf(px[p], a0.x, fmaf(py[p], a0.y, fmaf(pz[p], a0.z, a0.w)));
            float s1 = fmaf(px[p], a1.x, fmaf(py[p], a1.y, fmaf(pz[p], a1.z, a1.w)));
            float s2 = fmaf(px[p], a2.x, fmaf(py[p], a2.y, fmaf(pz[p], a2.z, a2.w)));
            float s3 = fmaf(px[p], a3.x, fmaf(py[p], a3.y, fmaf(pz[p], a3.z, a3.w)));
            m[p] = fminf(fminf(fminf(m[p], s0), fminf(s1, s2)), s3);
        }
    }

#pragma unroll
    for (int p = 0; p < P; ++p)
        minpart[(chunk * B + b) * M + i0 + p * 256] = m[p];
}

// Kernel 2: fold 128 chunk-partials, add ||p||^2, mean via block reduce + atomicAdd.
__global__ __launch_bounds__(256) void reduce_kernel(
        const float* __restrict__ pc, const float* __restrict__ minpart,
        float* __restrict__ out) {
    int e = blockIdx.x * 256 + threadIdx.x;  // [0, 16384)
    int b = e >> 12;
    int i = e & (M - 1);

    float v = 3.0e38f;
#pragma unroll 8
    for (int c = 0; c < NCHUNK; ++c)
        v = fminf(v, minpart[(c * B + b) * M + i]);

    float px = pc[(b * 3 + 0) * M + i];
    float py = pc[(b * 3 + 1) * M + i];
    float pz = pc[(b * 3 + 2) * M + i];
    float pn = fmaf(px, px, fmaf(py, py, pz * pz));
    float d = v + pn;

    // wave64 reduce
    for (int off = 32; off > 0; off >>= 1)
        d += __shfl_down(d, off, 64);
    __shared__ float smem[4];
    int lane = threadIdx.x & 63;
    int wid = threadIdx.x >> 6;
    if (lane == 0) smem[wid] = d;
    __syncthreads();
    if (threadIdx.x == 0) {
        float s = (smem[0] + smem[1]) + (smem[2] + smem[3]);
        atomicAdd(out, s * (1.0f / (float)BM));
    }
}

extern "C" void kernel_launch(void* const* d_in, const int* in_sizes, int n_in,
                              void* d_out, int out_size, void* d_ws, size_t ws_size,
                              hipStream_t stream) {
    const float* nm = (const float*)d_in[0];   // (4,3,32,32)
    const float* pc = (const float*)d_in[1];   // (4,3,4096)
    float* out = (float*)d_out;                // scalar

    float* minpart = (float*)d_ws;             // 128*16384*4 = 8 MiB

    // grid: 128 chunks x 4 pc-tiles x 4 batches = 2048 blocks = 8 waves/SIMD
    dist_kernel<<<dim3(NCHUNK, M / (256 * P), B), 256, 0, stream>>>(nm, pc, minpart, out);

    reduce_kernel<<<BM / 256, 256, 0, stream>>>(pc, minpart, out);
}